// Round 12
// baseline (326.991 us; speedup 1.0000x reference)
//
#include <hip/hip_runtime.h>

#define KCODES 512
#define DIM 64
#define NB 32
#define NH 64
#define NW 64
#define NPTS (NB*NH*NW)     // 131072
#define HW (NH*NW)          // 4096

// ---- output layout (floats) ----
#define O_OUT  0
#define O_LOSS 8388608
#define O_IDX  8388609
#define O_EMB  8519681
#define O_M    8552449
#define O_MM   8585217

// ---- workspace layout (floats) ----
#define W_DM   0
#define W_CNT  (KCODES*DIM)         // 32768
#define W_LOSS (W_CNT + KCODES)     // 33280
#define W_NEWM (W_LOSS + 1)         // 33281
#define W_C    (W_NEWM + KCODES)    // 33793
#define W_EHF  34308                // 32768 shorts (16384 floats), 16B-aligned
#define W_ELF  (W_EHF + 16384)      // 50692
#define W_TOTAL (W_ELF + 16384)     // 67076 floats ~ 268 KB

#define EPS_GAP 0.0625f

using bfrag = __attribute__((ext_vector_type(8))) short;
using f32x4 = __attribute__((ext_vector_type(4))) float;

__device__ __forceinline__ unsigned short f2bh(float x) {   // RNE fp32->bf16
    unsigned u = __float_as_uint(x);
    return (unsigned short)((u + 0x7FFFu + ((u >> 16) & 1u)) >> 16);
}
__device__ __forceinline__ float bf2f(unsigned short h) {
    return __uint_as_float(((unsigned)h) << 16);
}
__device__ __forceinline__ unsigned fmap(float s) {         // order-preserving
    unsigned b = __float_as_uint(s);
    return b ^ (unsigned)(((int)b >> 31) | (int)0x80000000);
}
__device__ __forceinline__ float finv(unsigned u) {
    unsigned b = (u & 0x80000000u) ? (u ^ 0x80000000u) : ~u;
    return __uint_as_float(b);
}

__global__ void cnorm_kernel(const float* __restrict__ emb, float* __restrict__ ws) {
    int k = blockIdx.x * blockDim.x + threadIdx.x;
    if (k >= KCODES) return;
    float s = 0.f;
    #pragma unroll
    for (int d = 0; d < DIM; ++d) { float v = emb[k*DIM + d]; s += v*v; }
    ws[W_C + k] = s;
}

// Convert codebook to bf16 hi/lo ONCE, in MFMA B-fragment order (validated
// r10/r11: absmax 50): short idx (((t8*2+h)*64+lane)*8+j) holds
// E[k=t8*16+(lane&15)][d=h*32+(lane>>4)*8+j].
__global__ void prep_kernel(const float* __restrict__ emb, float* __restrict__ ws) {
    int tid = blockIdx.x * 256 + threadIdx.x;    // 0..4095
    int k = tid >> 3, g = tid & 7;
    int h = g >> 2, kg = g & 3;
    int lane = kg*16 + (k & 15);
    int d0 = h*32 + kg*8;
    size_t dst = ((size_t)((k >> 4)*2 + h)*64 + lane)*8;
    unsigned hi[4], lo[4];
    #pragma unroll
    for (int jp = 0; jp < 4; ++jp) {
        float x0 = emb[k*64 + d0 + 2*jp], x1 = emb[k*64 + d0 + 2*jp + 1];
        unsigned short h0 = f2bh(x0), h1 = f2bh(x1);
        unsigned short l0 = f2bh(x0 - bf2f(h0)), l1 = f2bh(x1 - bf2f(h1));
        hi[jp] = (unsigned)h0 | ((unsigned)h1 << 16);
        lo[jp] = (unsigned)l0 | ((unsigned)l1 << 16);
    }
    unsigned short* EHF = (unsigned short*)(ws + W_EHF);
    unsigned short* ELF = (unsigned short*)(ws + W_ELF);
    *(uint4*)&EHF[dst] = make_uint4(hi[0], hi[1], hi[2], hi[3]);
    *(uint4*)&ELF[dst] = make_uint4(lo[0], lo[1], lo[2], lo[3]);
}

// Split-bf16 MFMA assign v3: wave = ONE 16-point M-tile (r11 halved: A-frags
// 16 regs not 32, tracking 12 not 24, no unroll -> no spill), block = 64 pts,
// 2048 blocks. B-frags streamed from L2-hot prep table (coalesced 1KB/instr).
// Math + frag layouts + rescue identical to r10/r11 (validated absmax 50).
__global__ __launch_bounds__(256, 4) void assign_kernel(
    const float* __restrict__ enc, const float* __restrict__ emb,
    const float* __restrict__ ws, float* __restrict__ out)
{
    __shared__ float XL[64*68];
    __shared__ int bestI[64];
    __shared__ int flagP[64];
    __shared__ int nflag;

    const int t  = threadIdx.x;
    const int lw = t & 63;
    const int wv = t >> 6;
    const int row16 = lw & 15, kgrp = lw >> 4;
    const int R = blockIdx.x;                    // one (b,h) row per block
    const int b = R >> 6, h = R & 63;

    if (t == 0) nflag = 0;

    // ---- stage X fp32 -> LDS (lane=point, wave=dim-group; as r9) ----
    {
        const float* base = enc + (size_t)b*64*HW + (size_t)h*64 + lw;
        #pragma unroll
        for (int it = 0; it < 4; ++it) {
            int d0 = (it*4 + wv)*4;
            float4 v = make_float4(base[(size_t)(d0+0)*HW], base[(size_t)(d0+1)*HW],
                                   base[(size_t)(d0+2)*HW], base[(size_t)(d0+3)*HW]);
            *(float4*)(&XL[lw*68 + d0]) = v;
        }
    }
    __syncthreads();

    // ---- A-frags (one M-tile = 16 points per wave), hi/lo in-reg ----
    bfrag ah[2], al[2];
    #pragma unroll
    for (int hf = 0; hf < 2; ++hf) {
        const float* src = &XL[(wv*16 + row16)*68 + hf*32 + kgrp*8];
        float4 f0 = *(const float4*)(src);
        float4 f1 = *(const float4*)(src + 4);
        unsigned short h0=f2bh(f0.x),h1=f2bh(f0.y),h2=f2bh(f0.z),h3=f2bh(f0.w);
        unsigned short h4=f2bh(f1.x),h5=f2bh(f1.y),h6=f2bh(f1.z),h7=f2bh(f1.w);
        ah[hf] = (bfrag){(short)h0,(short)h1,(short)h2,(short)h3,
                         (short)h4,(short)h5,(short)h6,(short)h7};
        al[hf] = (bfrag){(short)f2bh(f0.x-bf2f(h0)),(short)f2bh(f0.y-bf2f(h1)),
                         (short)f2bh(f0.z-bf2f(h2)),(short)f2bh(f0.w-bf2f(h3)),
                         (short)f2bh(f1.x-bf2f(h4)),(short)f2bh(f1.y-bf2f(h5)),
                         (short)f2bh(f1.z-bf2f(h6)),(short)f2bh(f1.w-bf2f(h7))};
    }

    const unsigned short* EHF = (const unsigned short*)(ws + W_EHF);
    const unsigned short* ELF = (const unsigned short*)(ws + W_ELF);
    const float* cns = ws + W_C;

    unsigned u1[4], u2[4]; int k1[4];
    #pragma unroll
    for (int r = 0; r < 4; ++r) { u1[r] = 0xFFFFFFFFu; u2[r] = 0xFFFFFFFFu; k1[r] = 0; }

    #pragma unroll 1     // keep loads inside the iteration: r11's hoist = spill
    for (int t8 = 0; t8 < 32; ++t8) {
        bfrag bh0 = *(const bfrag*)&EHF[((size_t)(t8*2+0)*64 + lw)*8];
        bfrag bh1 = *(const bfrag*)&EHF[((size_t)(t8*2+1)*64 + lw)*8];
        bfrag bl0 = *(const bfrag*)&ELF[((size_t)(t8*2+0)*64 + lw)*8];
        bfrag bl1 = *(const bfrag*)&ELF[((size_t)(t8*2+1)*64 + lw)*8];
        float cnv = cns[t8*16 + row16];
        int  kcol = t8*16 + row16;

        f32x4 acc = {0.f, 0.f, 0.f, 0.f};
        acc = __builtin_amdgcn_mfma_f32_16x16x32_bf16(ah[0], bh0, acc, 0,0,0);
        acc = __builtin_amdgcn_mfma_f32_16x16x32_bf16(ah[1], bh1, acc, 0,0,0);
        acc = __builtin_amdgcn_mfma_f32_16x16x32_bf16(ah[0], bl0, acc, 0,0,0);
        acc = __builtin_amdgcn_mfma_f32_16x16x32_bf16(ah[1], bl1, acc, 0,0,0);
        acc = __builtin_amdgcn_mfma_f32_16x16x32_bf16(al[0], bh0, acc, 0,0,0);
        acc = __builtin_amdgcn_mfma_f32_16x16x32_bf16(al[1], bh1, acc, 0,0,0);
        #pragma unroll
        for (int r = 0; r < 4; ++r) {
            float s = fmaf(-2.f, acc[r], cnv);
            unsigned u = fmap(s);
            bool win = u < u1[r];
            u2[r] = win ? u1[r] : (u < u2[r] ? u : u2[r]);
            k1[r] = win ? kcol : k1[r];
            u1[r] = win ? u : u1[r];
        }
    }

    // ---- cross-lane argmin (16 col-lanes) with second-best; flag ties ----
    #pragma unroll
    for (int r = 0; r < 4; ++r) {
        unsigned long long v = ((unsigned long long)u1[r] << 32) | (unsigned)k1[r];
        unsigned c2 = u2[r];
        #pragma unroll
        for (int off = 1; off < 16; off <<= 1) {
            unsigned long long ov = __shfl_xor(v, off, 64);
            unsigned oc2 = __shfl_xor(c2, off, 64);
            unsigned ob = (unsigned)(ov >> 32), mb = (unsigned)(v >> 32);
            bool win = ov < v;
            c2 = win ? (mb < oc2 ? mb : oc2) : (c2 < ob ? c2 : ob);
            v  = win ? ov : v;
        }
        if (row16 == 0) {
            int p = wv*16 + kgrp*4 + r;           // point = C-row within block
            bestI[p] = (int)(unsigned)v;
            float gap = finv(c2) - finv((unsigned)(v >> 32));
            if (gap < EPS_GAP) { int pos = atomicAdd(&nflag, 1); flagP[pos] = p; }
        }
    }
    __syncthreads();

    // ---- wave-parallel exact fp32 rescue (no barriers inside) ----
    int nf = nflag;
    for (int f = wv; f < nf; f += 4) {
        int p = flagP[f];
        float dot[8];
        #pragma unroll
        for (int c = 0; c < 8; ++c) dot[c] = 0.f;
        const float* er = emb + (size_t)(lw*8)*64;   // lane owns cw lw*8..+7
        for (int d4 = 0; d4 < 16; ++d4) {
            float4 xv = *(const float4*)(&XL[p*68 + d4*4]);   // LDS broadcast
            #pragma unroll
            for (int c = 0; c < 8; ++c) {
                float4 ev = *(const float4*)(er + c*64 + d4*4);
                dot[c] = fmaf(xv.x, ev.x, fmaf(xv.y, ev.y,
                         fmaf(xv.z, ev.z, fmaf(xv.w, ev.w, dot[c]))));
            }
        }
        unsigned long long vb = 0xFFFFFFFFFFFFFFFFull;
        #pragma unroll
        for (int c = 0; c < 8; ++c) {
            float s = cns[lw*8 + c] - 2.f*dot[c];
            unsigned long long vv = ((unsigned long long)fmap(s) << 32) | (unsigned)(lw*8 + c);
            vb = (vv < vb) ? vv : vb;
        }
        #pragma unroll
        for (int off = 1; off < 64; off <<= 1) {
            unsigned long long ov = __shfl_xor(vb, off, 64);
            vb = (ov < vb) ? ov : vb;
        }
        if (lw == 0) bestI[p] = (int)(unsigned)vb;
    }
    __syncthreads();

    if (t < 64) out[O_IDX + (size_t)R*64 + t] = (float)bestI[t];
}

// unchanged (r9): fused dm/cnt LDS accumulation + quantized store + loss
__global__ __launch_bounds__(512, 1) void scatter_kernel(
    const float* __restrict__ enc, const float* __restrict__ emb,
    float* __restrict__ out, float* __restrict__ ws)
{
    __shared__ float dmL[KCODES][DIM+1];
    __shared__ float cntL[KCODES];
    __shared__ float redL[8];

    const int t  = threadIdx.x;
    const int w  = t & 63;
    const int wv = t >> 6;
    const int pg = w >> 4, dl = w & 15;

    float* dmf = &dmL[0][0];
    for (int i = t; i < KCODES*(DIM+1); i += 512) dmf[i] = 0.f;
    if (t < KCODES) cntL[t] = 0.f;
    __syncthreads();

    const int R = blockIdx.x * 8 + wv;
    const int b = R >> 6, h = R & 63;
    const float* base  = enc + (size_t)b*(64*HW) + (size_t)h*64;
    float*       obase = out + O_OUT + (size_t)b*(64*HW) + (size_t)h*64;

    const int bidx = (int)out[O_IDX + (size_t)R*64 + w];
    atomicAdd(&cntL[bidx], 1.0f);
    float lsum = 0.f;

    #pragma unroll
    for (int c = 0; c < 4; ++c) {
        #pragma unroll
        for (int jj = 0; jj < 16; ++jj) {
            int p  = jj*4 + pg;
            int kb = __shfl(bidx, p, 64);
            int d  = c*16 + dl;
            float xv = base[(size_t)d*HW + p];
            atomicAdd(&dmL[kb][d], xv);
            float q = emb[kb*64 + d];
            obase[(size_t)d*HW + p] = q;
            float df = q - xv;
            lsum = fmaf(df, df, lsum);
        }
    }

    #pragma unroll
    for (int off = 32; off >= 1; off >>= 1) lsum += __shfl_down(lsum, off, 64);
    if (w == 0) redL[wv] = lsum;
    __syncthreads();
    if (t == 0) {
        float s = 0.f;
        #pragma unroll
        for (int v = 0; v < 8; ++v) s += redL[v];
        atomicAdd(&ws[W_LOSS], s);
    }

    for (int k = wv*64; k < wv*64 + 64; ++k) {
        float c = cntL[k];
        if (c == 0.f) continue;
        atomicAdd(&ws[W_DM + k*64 + w], dmL[k][w]);
        if (w == 0) atomicAdd(&ws[W_CNT + k], c);
    }
}

__global__ void finalizeA(const float* __restrict__ emaM,
                          float* __restrict__ out, float* __restrict__ ws)
{
    __shared__ float red[512];
    int k = threadIdx.x;
    float nM = 0.99f * emaM[k] + 0.01f * ws[W_CNT + k];
    red[k] = nM;
    __syncthreads();
    for (int s = 256; s >= 1; s >>= 1) {
        if (k < s) red[k] += red[k + s];
        __syncthreads();
    }
    float Ntot = red[0];
    float sm = (nM + 1e-5f) / (Ntot + 1e-5f * (float)KCODES) * Ntot;
    ws[W_NEWM + k] = sm;
    out[O_MM + k] = sm;
    if (k == 0) out[O_LOSS] = 0.25f * ws[W_LOSS] / (float)((size_t)NPTS * DIM);
}

__global__ void finalizeB(const float* __restrict__ emam,
                          float* __restrict__ out, const float* __restrict__ ws)
{
    int i = blockIdx.x * blockDim.x + threadIdx.x;
    int k = i >> 6;
    float nm = 0.99f * emam[i] + 0.01f * ws[W_DM + i];
    out[O_M + i] = nm;
    out[O_EMB + i] = nm / ws[W_NEWM + k];
}

extern "C" void kernel_launch(void* const* d_in, const int* in_sizes, int n_in,
                              void* d_out, int out_size, void* d_ws, size_t ws_size,
                              hipStream_t stream)
{
    const float* enc  = (const float*)d_in[0];
    const float* emb  = (const float*)d_in[1];
    const float* emam = (const float*)d_in[2];
    const float* emaM = (const float*)d_in[3];
    float* out = (float*)d_out;
    float* ws  = (float*)d_ws;

    hipMemsetAsync(ws, 0, (size_t)33794 * sizeof(float), stream);
    cnorm_kernel<<<2, 256, 0, stream>>>(emb, ws);
    prep_kernel<<<16, 256, 0, stream>>>(emb, ws);
    assign_kernel<<<NPTS/64, 256, 0, stream>>>(enc, emb, ws, out);   // 2048 blocks
    scatter_kernel<<<256, 512, 0, stream>>>(enc, emb, out, ws);
    finalizeA<<<1, 512, 0, stream>>>(emaM, out, ws);
    finalizeB<<<(KCODES*DIM)/256, 256, 0, stream>>>(emam, out, ws);
}

// Round 13
// 298.196 us; speedup vs baseline: 1.0966x; 1.0966x over previous
//
#include <hip/hip_runtime.h>

#define KCODES 512
#define DIM 64
#define NB 32
#define NH 64
#define NW 64
#define NPTS (NB*NH*NW)     // 131072
#define HW (NH*NW)          // 4096

// ---- output layout (floats) ----
#define O_OUT  0
#define O_LOSS 8388608
#define O_IDX  8388609
#define O_EMB  8519681
#define O_M    8552449
#define O_MM   8585217

// ---- workspace layout (floats) ----
#define W_DM   0
#define W_CNT  (KCODES*DIM)         // 32768
#define W_LOSS (W_CNT + KCODES)     // 33280
#define W_NEWM (W_LOSS + 1)         // 33281
#define W_C    (W_NEWM + KCODES)    // 33793
#define W_EHF  34308                // 32768 shorts, 16B-aligned
#define W_ELF  (W_EHF + 16384)      // 50692
#define W_TOTAL (W_ELF + 16384)     // 67076 floats

#define EPS_GAP 0.0625f

using bfrag = __attribute__((ext_vector_type(8))) short;
using f32x4 = __attribute__((ext_vector_type(4))) float;

__device__ __forceinline__ unsigned short f2bh(float x) {   // RNE fp32->bf16
    unsigned u = __float_as_uint(x);
    return (unsigned short)((u + 0x7FFFu + ((u >> 16) & 1u)) >> 16);
}
__device__ __forceinline__ float bf2f(unsigned short h) {
    return __uint_as_float(((unsigned)h) << 16);
}
__device__ __forceinline__ unsigned fmap(float s) {
    unsigned b = __float_as_uint(s);
    return b ^ (unsigned)(((int)b >> 31) | (int)0x80000000);
}

__global__ void cnorm_kernel(const float* __restrict__ emb, float* __restrict__ ws) {
    int k = blockIdx.x * blockDim.x + threadIdx.x;
    if (k >= KCODES) return;
    float s = 0.f;
    #pragma unroll
    for (int d = 0; d < DIM; ++d) { float v = emb[k*DIM + d]; s += v*v; }
    ws[W_C + k] = s;
}

// Codebook -> bf16 hi/lo ONCE, MFMA B-fragment order (validated r10-r12):
// short idx (((t8*2+h)*64+lane)*8+j) = E[k=t8*16+(lane&15)][d=h*32+(lane>>4)*8+j]
__global__ void prep_kernel(const float* __restrict__ emb, float* __restrict__ ws) {
    int tid = blockIdx.x * 256 + threadIdx.x;    // 0..4095
    int k = tid >> 3, g = tid & 7;
    int h = g >> 2, kg = g & 3;
    int lane = kg*16 + (k & 15);
    int d0 = h*32 + kg*8;
    size_t dst = ((size_t)((k >> 4)*2 + h)*64 + lane)*8;
    unsigned hi[4], lo[4];
    #pragma unroll
    for (int jp = 0; jp < 4; ++jp) {
        float x0 = emb[k*64 + d0 + 2*jp], x1 = emb[k*64 + d0 + 2*jp + 1];
        unsigned short h0 = f2bh(x0), h1 = f2bh(x1);
        unsigned short l0 = f2bh(x0 - bf2f(h0)), l1 = f2bh(x1 - bf2f(h1));
        hi[jp] = (unsigned)h0 | ((unsigned)h1 << 16);
        lo[jp] = (unsigned)l0 | ((unsigned)l1 << 16);
    }
    unsigned short* EHF = (unsigned short*)(ws + W_EHF);
    unsigned short* ELF = (unsigned short*)(ws + W_ELF);
    *(uint4*)&EHF[dst] = make_uint4(hi[0], hi[1], hi[2], hi[3]);
    *(uint4*)&ELF[dst] = make_uint4(lo[0], lo[1], lo[2], lo[3]);
}

// Split-bf16 MFMA assign v4 = r10's NO-SPILL skeleton (B-frags via LDS) with
// the prep table replacing per-block conversion: tile staging is 8 plain
// uint4 copies/thread (32KB), frags then ds_read_b128 exactly as r10.
// r11/r12's global-direct frag loads caused wholesale scratch allocation
// (WRITE 162->187MB); r10's LDS path measured WRITE 544KB, VGPR 88.
__global__ __launch_bounds__(256, 2) void assign_kernel(
    const float* __restrict__ enc, const float* __restrict__ emb,
    const float* __restrict__ ws, float* __restrict__ out)
{
    __shared__ float XL[128*68];                 // fp32 X (A-build + rescue)
    __shared__ unsigned short EHT[8192];         // 16KB: hi tile, frag order
    __shared__ unsigned short ELT[8192];         // 16KB: lo tile
    __shared__ float cnT[128];
    __shared__ int   bestI[128];
    __shared__ int   flagP[128];
    __shared__ int   nflag;

    const int t  = threadIdx.x;
    const int lw = t & 63;
    const int wv = t >> 6;
    const int row16 = lw & 15, kgrp = lw >> 4;
    const int R0 = blockIdx.x * 2;

    if (t == 0) nflag = 0;

    // ---- stage X fp32 -> LDS (coalesced, as r9/r10) ----
    #pragma unroll
    for (int r2 = 0; r2 < 2; ++r2) {
        int R = R0 + r2, b = R >> 6, h = R & 63;
        const float* base = enc + (size_t)b*64*HW + (size_t)h*64 + lw;
        int p = r2*64 + lw;
        #pragma unroll
        for (int it = 0; it < 4; ++it) {
            int d0 = (it*4 + wv)*4;
            float4 v = make_float4(base[(size_t)(d0+0)*HW], base[(size_t)(d0+1)*HW],
                                   base[(size_t)(d0+2)*HW], base[(size_t)(d0+3)*HW]);
            *(float4*)(&XL[p*68 + d0]) = v;
        }
    }
    __syncthreads();

    // ---- A-frags: 2 M-tiles per wave, hi/lo converted in-reg once (r10) ----
    bfrag ah[2][2], al[2][2];
    #pragma unroll
    for (int mi = 0; mi < 2; ++mi) {
        int Mt = wv*2 + mi;
        #pragma unroll
        for (int hf = 0; hf < 2; ++hf) {
            const float* src = &XL[(Mt*16 + row16)*68 + hf*32 + kgrp*8];
            float4 f0 = *(const float4*)(src);
            float4 f1 = *(const float4*)(src + 4);
            unsigned short h0=f2bh(f0.x),h1=f2bh(f0.y),h2=f2bh(f0.z),h3=f2bh(f0.w);
            unsigned short h4=f2bh(f1.x),h5=f2bh(f1.y),h6=f2bh(f1.z),h7=f2bh(f1.w);
            ah[mi][hf] = (bfrag){(short)h0,(short)h1,(short)h2,(short)h3,
                                 (short)h4,(short)h5,(short)h6,(short)h7};
            al[mi][hf] = (bfrag){(short)f2bh(f0.x-bf2f(h0)),(short)f2bh(f0.y-bf2f(h1)),
                                 (short)f2bh(f0.z-bf2f(h2)),(short)f2bh(f0.w-bf2f(h3)),
                                 (short)f2bh(f1.x-bf2f(h4)),(short)f2bh(f1.y-bf2f(h5)),
                                 (short)f2bh(f1.z-bf2f(h6)),(short)f2bh(f1.w-bf2f(h7))};
        }
    }

    const unsigned short* EHF = (const unsigned short*)(ws + W_EHF);
    const unsigned short* ELF = (const unsigned short*)(ws + W_ELF);

    float b1[2][4], b2[2][4]; int k1[2][4];
    #pragma unroll
    for (int mi = 0; mi < 2; ++mi)
        #pragma unroll
        for (int r = 0; r < 4; ++r) { b1[mi][r] = 3.402823466e38f; b2[mi][r] = 3.402823466e38f; k1[mi][r] = 0; }

    for (int tile = 0; tile < 4; ++tile) {
        __syncthreads();             // prior tile's EHT/ELT reads done
        // stage tile: 2 x 16KB plain copies (no conversion -- prep did it)
        {
            const uint4* hsrc = (const uint4*)(EHF + (size_t)tile*8192);
            const uint4* lsrc = (const uint4*)(ELF + (size_t)tile*8192);
            uint4* hdst = (uint4*)EHT;
            uint4* ldst = (uint4*)ELT;
            #pragma unroll
            for (int q = 0; q < 4; ++q) hdst[t + q*256] = hsrc[t + q*256];
            #pragma unroll
            for (int q = 0; q < 4; ++q) ldst[t + q*256] = lsrc[t + q*256];
        }
        if (t < 128) cnT[t] = ws[W_C + tile*128 + t];
        __syncthreads();

        for (int nt = 0; nt < 8; ++nt) {
            bfrag bh0 = *(bfrag*)&EHT[((nt*2+0)*64 + lw)*8];
            bfrag bh1 = *(bfrag*)&EHT[((nt*2+1)*64 + lw)*8];
            bfrag bl0 = *(bfrag*)&ELT[((nt*2+0)*64 + lw)*8];
            bfrag bl1 = *(bfrag*)&ELT[((nt*2+1)*64 + lw)*8];
            float cnv = cnT[nt*16 + row16];
            int  kcol = tile*128 + nt*16 + row16;

            #pragma unroll
            for (int mi = 0; mi < 2; ++mi) {
                f32x4 acc = {0.f, 0.f, 0.f, 0.f};
                acc = __builtin_amdgcn_mfma_f32_16x16x32_bf16(ah[mi][0], bh0, acc, 0,0,0);
                acc = __builtin_amdgcn_mfma_f32_16x16x32_bf16(ah[mi][1], bh1, acc, 0,0,0);
                acc = __builtin_amdgcn_mfma_f32_16x16x32_bf16(ah[mi][0], bl0, acc, 0,0,0);
                acc = __builtin_amdgcn_mfma_f32_16x16x32_bf16(ah[mi][1], bl1, acc, 0,0,0);
                acc = __builtin_amdgcn_mfma_f32_16x16x32_bf16(al[mi][0], bh0, acc, 0,0,0);
                acc = __builtin_amdgcn_mfma_f32_16x16x32_bf16(al[mi][1], bh1, acc, 0,0,0);
                #pragma unroll
                for (int r = 0; r < 4; ++r) {
                    float s = fmaf(-2.f, acc[r], cnv);
                    if (s < b1[mi][r]) { b2[mi][r] = b1[mi][r]; b1[mi][r] = s; k1[mi][r] = kcol; }
                    else if (s < b2[mi][r]) b2[mi][r] = s;
                }
            }
        }
    }

    // ---- cross-lane argmin (16 col-lanes) with second-best; flag ties ----
    #pragma unroll
    for (int mi = 0; mi < 2; ++mi)
        #pragma unroll
        for (int r = 0; r < 4; ++r) {
            float b = b1[mi][r], c2 = b2[mi][r]; int kk = k1[mi][r];
            #pragma unroll
            for (int off = 1; off < 16; off <<= 1) {
                float ob  = __shfl_xor(b,  off, 64);
                int   ok  = __shfl_xor(kk, off, 64);
                float oc2 = __shfl_xor(c2, off, 64);
                bool win = (ob < b) || (ob == b && ok < kk);
                if (win) { c2 = fminf(b, oc2); b = ob; kk = ok; }
                else     { c2 = fminf(c2, ob); }
            }
            if (row16 == 0) {
                int p = (wv*2 + mi)*16 + kgrp*4 + r;
                bestI[p] = kk;
                if (c2 - b < EPS_GAP) { int pos = atomicAdd(&nflag, 1); flagP[pos] = p; }
            }
        }
    __syncthreads();

    // ---- wave-parallel exact fp32 rescue (compacted; no barriers inside) ----
    int nf = nflag;
    for (int f = wv; f < nf; f += 4) {
        int p = flagP[f];
        float dot[8];
        #pragma unroll
        for (int c = 0; c < 8; ++c) dot[c] = 0.f;
        const float* er = emb + (size_t)(lw*8)*64;   // lane owns cw lw*8..+7
        for (int d4 = 0; d4 < 16; ++d4) {
            float4 xv = *(const float4*)(&XL[p*68 + d4*4]);   // LDS broadcast
            #pragma unroll
            for (int c = 0; c < 8; ++c) {
                float4 ev = *(const float4*)(er + c*64 + d4*4);
                dot[c] = fmaf(xv.x, ev.x, fmaf(xv.y, ev.y,
                         fmaf(xv.z, ev.z, fmaf(xv.w, ev.w, dot[c]))));
            }
        }
        unsigned long long vb = 0xFFFFFFFFFFFFFFFFull;
        #pragma unroll
        for (int c = 0; c < 8; ++c) {
            float s = ws[W_C + lw*8 + c] - 2.f*dot[c];
            unsigned long long vv = ((unsigned long long)fmap(s) << 32) | (unsigned)(lw*8 + c);
            vb = (vv < vb) ? vv : vb;
        }
        #pragma unroll
        for (int off = 1; off < 64; off <<= 1) {
            unsigned long long ov = __shfl_xor(vb, off, 64);
            vb = (ov < vb) ? ov : vb;
        }
        if (lw == 0) bestI[p] = (int)(unsigned)vb;
    }
    __syncthreads();

    if (t < 128) out[O_IDX + (size_t)R0*64 + t] = (float)bestI[t];
}

// scatter v2: 1024 threads = 16 waves (was 8). Waves 0-7: enc load + dmL
// atomics; waves 8-15: quantized gather + out store + loss (enc re-read
// is L2-hot). Flush over 16 waves. Pure TLP for a latency-bound kernel.
__global__ __launch_bounds__(1024, 1) void scatter_kernel(
    const float* __restrict__ enc, const float* __restrict__ emb,
    float* __restrict__ out, float* __restrict__ ws)
{
    __shared__ float dmL[KCODES][DIM+1];
    __shared__ float cntL[KCODES];
    __shared__ float redL[16];

    const int t  = threadIdx.x;
    const int w  = t & 63;
    const int wv = t >> 6;           // 0..15
    const int rw = wv & 7;           // row slot
    const int role = wv >> 3;        // 0: accumulate, 1: gather/store/loss
    const int pg = w >> 4, dl = w & 15;

    float* dmf = &dmL[0][0];
    for (int i = t; i < KCODES*(DIM+1); i += 1024) dmf[i] = 0.f;
    if (t < KCODES) cntL[t] = 0.f;
    __syncthreads();

    const int R = blockIdx.x * 8 + rw;
    const int b = R >> 6, h = R & 63;
    const float* base  = enc + (size_t)b*(64*HW) + (size_t)h*64;
    float*       obase = out + O_OUT + (size_t)b*(64*HW) + (size_t)h*64;

    const int bidx = (int)out[O_IDX + (size_t)R*64 + w];
    float lsum = 0.f;

    if (role == 0) {
        atomicAdd(&cntL[bidx], 1.0f);
        #pragma unroll
        for (int c = 0; c < 4; ++c) {
            #pragma unroll
            for (int jj = 0; jj < 16; ++jj) {
                int p  = jj*4 + pg;
                int kb = __shfl(bidx, p, 64);
                int d  = c*16 + dl;
                atomicAdd(&dmL[kb][d], base[(size_t)d*HW + p]);
            }
        }
    } else {
        #pragma unroll
        for (int c = 0; c < 4; ++c) {
            #pragma unroll
            for (int jj = 0; jj < 16; ++jj) {
                int p  = jj*4 + pg;
                int kb = __shfl(bidx, p, 64);
                int d  = c*16 + dl;
                float xv = base[(size_t)d*HW + p];
                float q  = emb[kb*64 + d];
                obase[(size_t)d*HW + p] = q;
                float df = q - xv;
                lsum = fmaf(df, df, lsum);
            }
        }
    }

    #pragma unroll
    for (int off = 32; off >= 1; off >>= 1) lsum += __shfl_down(lsum, off, 64);
    if (w == 0) redL[wv] = lsum;
    __syncthreads();
    if (t == 0) {
        float s = 0.f;
        #pragma unroll
        for (int v = 8; v < 16; ++v) s += redL[v];
        atomicAdd(&ws[W_LOSS], s);
    }

    // flush: wave wv owns 32 rows; lane = dim (coalesced 256B atomic runs)
    for (int k = wv*32; k < wv*32 + 32; ++k) {
        float c = cntL[k];
        if (c == 0.f) continue;
        atomicAdd(&ws[W_DM + k*64 + w], dmL[k][w]);
        if (w == 0) atomicAdd(&ws[W_CNT + k], c);
    }
}

__global__ void finalizeA(const float* __restrict__ emaM,
                          float* __restrict__ out, float* __restrict__ ws)
{
    __shared__ float red[512];
    int k = threadIdx.x;
    float nM = 0.99f * emaM[k] + 0.01f * ws[W_CNT + k];
    red[k] = nM;
    __syncthreads();
    for (int s = 256; s >= 1; s >>= 1) {
        if (k < s) red[k] += red[k + s];
        __syncthreads();
    }
    float Ntot = red[0];
    float sm = (nM + 1e-5f) / (Ntot + 1e-5f * (float)KCODES) * Ntot;
    ws[W_NEWM + k] = sm;
    out[O_MM + k] = sm;
    if (k == 0) out[O_LOSS] = 0.25f * ws[W_LOSS] / (float)((size_t)NPTS * DIM);
}

__global__ void finalizeB(const float* __restrict__ emam,
                          float* __restrict__ out, const float* __restrict__ ws)
{
    int i = blockIdx.x * blockDim.x + threadIdx.x;
    int k = i >> 6;
    float nm = 0.99f * emam[i] + 0.01f * ws[W_DM + i];
    out[O_M + i] = nm;
    out[O_EMB + i] = nm / ws[W_NEWM + k];
}

extern "C" void kernel_launch(void* const* d_in, const int* in_sizes, int n_in,
                              void* d_out, int out_size, void* d_ws, size_t ws_size,
                              hipStream_t stream)
{
    const float* enc  = (const float*)d_in[0];
    const float* emb  = (const float*)d_in[1];
    const float* emam = (const float*)d_in[2];
    const float* emaM = (const float*)d_in[3];
    float* out = (float*)d_out;
    float* ws  = (float*)d_ws;

    hipMemsetAsync(ws, 0, (size_t)33794 * sizeof(float), stream);
    cnorm_kernel<<<2, 256, 0, stream>>>(emb, ws);
    prep_kernel<<<16, 256, 0, stream>>>(emb, ws);
    assign_kernel<<<NPTS/128, 256, 0, stream>>>(enc, emb, ws, out);   // 1024 blocks
    scatter_kernel<<<256, 1024, 0, stream>>>(enc, emb, out, ws);
    finalizeA<<<1, 512, 0, stream>>>(emaM, out, ws);
    finalizeB<<<(KCODES*DIM)/256, 256, 0, stream>>>(emam, out, ws);
}

// Round 14
// 238.286 us; speedup vs baseline: 1.3723x; 1.2514x over previous
//
#include <hip/hip_runtime.h>

#define KCODES 512
#define DIM 64
#define NB 32
#define NH 64
#define NW 64
#define NPTS (NB*NH*NW)     // 131072
#define HW (NH*NW)          // 4096

// ---- output layout (floats) ----
#define O_OUT  0
#define O_LOSS 8388608
#define O_IDX  8388609
#define O_EMB  8519681
#define O_M    8552449
#define O_MM   8585217

// ---- workspace layout (floats) ----
#define W_DM   0                    // 32768
#define W_CNT  32768                // 512
#define W_LOSS 33280                // 1
#define W_SUMM 33281                // 1: sum of ema_M input
#define W_C    33282                // 512 codeword sq-norms
#define W_ZERO 33282                // memset extent (W_DM..W_SUMM)

#define XPAD 68
#define EPAD 68

// cnorm + side-effect: Sigma(ema_M) for the closed-form Ntot
__global__ void cnorm_kernel(const float* __restrict__ emb,
                             const float* __restrict__ emaM,
                             float* __restrict__ ws) {
    int k = blockIdx.x * blockDim.x + threadIdx.x;
    if (k >= KCODES) return;
    float s = 0.f;
    #pragma unroll
    for (int d = 0; d < DIM; ++d) { float v = emb[k*DIM + d]; s += v*v; }
    ws[W_C + k] = s;
    float m = emaM[k];
    #pragma unroll
    for (int off = 32; off >= 1; off >>= 1) m += __shfl_down(m, off, 64);
    if ((k & 63) == 0) atomicAdd(&ws[W_SUMM], m);
}

// r9's proven assign (142us, VGPR 100, no spill): register-tiled fp32 GEMM,
// 128 pts x 512 cw per block, 8x8 microtile, idx output only.
// MFMA variants r10-r13 all lost to compiler scratch allocation
// (WRITE_SIZE 93-187MB); this structure measures WRITE 544KB.
__global__ __launch_bounds__(256, 2) void assign_kernel(
    const float* __restrict__ enc, const float* __restrict__ emb,
    float* __restrict__ out, float* __restrict__ ws)
{
    __shared__ float XL[128*XPAD];   // [point][d]
    __shared__ float EL[128*EPAD];   // [cw][d]
    __shared__ float cnT[128];
    __shared__ int   bestI[128];

    const int t  = threadIdx.x;
    const int tx = t & 15;
    const int ty = t >> 4;
    const int wv = t >> 6, w = t & 63;
    const int R0 = blockIdx.x * 2;

    // stage X: thread = (point w, dim-quad); 4 coalesced b32 loads ->
    // one ds_write_b128 (bank-quad (p+q) mod 8: conflict-free)
    #pragma unroll
    for (int r2 = 0; r2 < 2; ++r2) {
        int R = R0 + r2, b = R >> 6, h = R & 63;
        const float* base = enc + (size_t)b*64*HW + (size_t)h*64 + w;
        int p = r2*64 + w;
        #pragma unroll
        for (int it = 0; it < 4; ++it) {
            int d0 = (it*4 + wv)*4;
            float4 v = make_float4(base[(size_t)(d0+0)*HW], base[(size_t)(d0+1)*HW],
                                   base[(size_t)(d0+2)*HW], base[(size_t)(d0+3)*HW]);
            *(float4*)(&XL[p*XPAD + d0]) = v;
        }
    }

    float best[8]; int bidx[8];
    #pragma unroll
    for (int i = 0; i < 8; ++i) { best[i] = 3.402823466e38f; bidx[i] = 0; }

    for (int tile = 0; tile < 4; ++tile) {
        __syncthreads();             // prior tile's EL reads done
        const float* esrc = emb + (size_t)tile*128*64;
        #pragma unroll
        for (int it = 0; it < 8; ++it) {
            int idx = t + it*256;
            *(float4*)(&EL[(idx >> 4)*EPAD + (idx & 15)*4]) =
                *(const float4*)(esrc + (idx >> 4)*64 + (idx & 15)*4);
        }
        if (t < 128) cnT[t] = ws[W_C + tile*128 + t];
        __syncthreads();

        float acc[8][8];
        #pragma unroll
        for (int i = 0; i < 8; ++i)
            #pragma unroll
            for (int j = 0; j < 8; ++j) acc[i][j] = 0.f;

        for (int c = 0; c < 16; ++c) {
            float4 xf[8], ef[8];
            #pragma unroll
            for (int i = 0; i < 8; ++i) {    // 16-lane broadcast reads
                int p = 2*ty + (i&1) + 32*(i>>1);
                xf[i] = *(const float4*)(&XL[p*XPAD + c*4]);
            }
            #pragma unroll
            for (int j = 0; j < 8; ++j) {    // 16 rows: 2 addrs/quad = free
                int r = tx + 16*j;
                ef[j] = *(const float4*)(&EL[r*EPAD + c*4]);
            }
            #pragma unroll
            for (int i = 0; i < 8; ++i)
                #pragma unroll
                for (int j = 0; j < 8; ++j) {
                    acc[i][j] = fmaf(xf[i].x, ef[j].x, acc[i][j]);
                    acc[i][j] = fmaf(xf[i].y, ef[j].y, acc[i][j]);
                    acc[i][j] = fmaf(xf[i].z, ef[j].z, acc[i][j]);
                    acc[i][j] = fmaf(xf[i].w, ef[j].w, acc[i][j]);
                }
        }

        #pragma unroll
        for (int j = 0; j < 8; ++j) {
            int k = tile*128 + tx + 16*j;
            float cn = cnT[tx + 16*j];
            #pragma unroll
            for (int i = 0; i < 8; ++i) {
                float s = cn - 2.f*acc[i][j];
                if (s < best[i] || (s == best[i] && k < bidx[i])) { best[i] = s; bidx[i] = k; }
            }
        }
    }

    // cross-lane argmin over the 16 tx-lanes sharing each point
    #pragma unroll
    for (int i = 0; i < 8; ++i) {
        float b = best[i]; int kx = bidx[i];
        #pragma unroll
        for (int off = 1; off < 16; off <<= 1) {
            float ob = __shfl_xor(b, off, 64);
            int   ok = __shfl_xor(kx, off, 64);
            if (ob < b || (ob == b && ok < kx)) { b = ob; kx = ok; }
        }
        if (tx == 0) bestI[2*ty + (i&1) + 32*(i>>1)] = kx;
    }
    __syncthreads();
    if (t < 128) out[O_IDX + (size_t)R0*64 + t] = (float)bestI[t];
}

// scatter v2: 1024 threads = 16 waves. Waves 0-7: enc load + dmL atomics;
// waves 8-15: quantized gather + out store + loss (enc re-read L2-hot).
// Flush over 16 waves. TLP for a latency-bound kernel.
__global__ __launch_bounds__(1024, 1) void scatter_kernel(
    const float* __restrict__ enc, const float* __restrict__ emb,
    float* __restrict__ out, float* __restrict__ ws)
{
    __shared__ float dmL[KCODES][DIM+1];
    __shared__ float cntL[KCODES];
    __shared__ float redL[16];

    const int t  = threadIdx.x;
    const int w  = t & 63;
    const int wv = t >> 6;           // 0..15
    const int rw = wv & 7;           // row slot
    const int role = wv >> 3;        // 0: accumulate, 1: gather/store/loss
    const int pg = w >> 4, dl = w & 15;

    float* dmf = &dmL[0][0];
    for (int i = t; i < KCODES*(DIM+1); i += 1024) dmf[i] = 0.f;
    if (t < KCODES) cntL[t] = 0.f;
    __syncthreads();

    const int R = blockIdx.x * 8 + rw;
    const int b = R >> 6, h = R & 63;
    const float* base  = enc + (size_t)b*(64*HW) + (size_t)h*64;
    float*       obase = out + O_OUT + (size_t)b*(64*HW) + (size_t)h*64;

    const int bidx = (int)out[O_IDX + (size_t)R*64 + w];
    float lsum = 0.f;

    if (role == 0) {
        atomicAdd(&cntL[bidx], 1.0f);
        #pragma unroll
        for (int c = 0; c < 4; ++c) {
            #pragma unroll
            for (int jj = 0; jj < 16; ++jj) {
                int p  = jj*4 + pg;
                int kb = __shfl(bidx, p, 64);
                int d  = c*16 + dl;
                atomicAdd(&dmL[kb][d], base[(size_t)d*HW + p]);
            }
        }
    } else {
        #pragma unroll
        for (int c = 0; c < 4; ++c) {
            #pragma unroll
            for (int jj = 0; jj < 16; ++jj) {
                int p  = jj*4 + pg;
                int kb = __shfl(bidx, p, 64);
                int d  = c*16 + dl;
                float xv = base[(size_t)d*HW + p];
                float q  = emb[kb*64 + d];
                obase[(size_t)d*HW + p] = q;
                float df = q - xv;
                lsum = fmaf(df, df, lsum);
            }
        }
    }

    #pragma unroll
    for (int off = 32; off >= 1; off >>= 1) lsum += __shfl_down(lsum, off, 64);
    if (w == 0) redL[wv] = lsum;
    __syncthreads();
    if (t == 0) {
        float s = 0.f;
        #pragma unroll
        for (int v = 8; v < 16; ++v) s += redL[v];
        atomicAdd(&ws[W_LOSS], s);
    }

    // flush: wave wv owns 32 rows; lane = dim (coalesced 256B atomic runs)
    for (int k = wv*32; k < wv*32 + 32; ++k) {
        float c = cntL[k];
        if (c == 0.f) continue;
        atomicAdd(&ws[W_DM + k*64 + w], dmL[k][w]);
        if (w == 0) atomicAdd(&ws[W_CNT + k], c);
    }
}

// Single fully-parallel finalize: Ntot closed form (0.99*SumEmaM + 0.01*NPTS)
// removes the serial single-block reduction kernel.
__global__ void finalize_kernel(const float* __restrict__ emam,
                                const float* __restrict__ emaM,
                                float* __restrict__ out,
                                const float* __restrict__ ws)
{
    int i = blockIdx.x * blockDim.x + threadIdx.x;  // 0..32767
    int k = i >> 6;
    float Ntot = 0.99f * ws[W_SUMM] + 0.01f * (float)NPTS;
    float nM = 0.99f * emaM[k] + 0.01f * ws[W_CNT + k];
    float sm = (nM + 1e-5f) / (Ntot + 1e-5f * (float)KCODES) * Ntot;
    float nm = 0.99f * emam[i] + 0.01f * ws[W_DM + i];
    out[O_M + i] = nm;
    out[O_EMB + i] = nm / sm;
    if ((i & 63) == 0) out[O_MM + k] = sm;
    if (i == 0) out[O_LOSS] = 0.25f * ws[W_LOSS] / (float)((size_t)NPTS * DIM);
}

extern "C" void kernel_launch(void* const* d_in, const int* in_sizes, int n_in,
                              void* d_out, int out_size, void* d_ws, size_t ws_size,
                              hipStream_t stream)
{
    const float* enc  = (const float*)d_in[0];
    const float* emb  = (const float*)d_in[1];
    const float* emam = (const float*)d_in[2];
    const float* emaM = (const float*)d_in[3];
    float* out = (float*)d_out;
    float* ws  = (float*)d_ws;

    hipMemsetAsync(ws, 0, (size_t)W_ZERO * sizeof(float), stream);
    cnorm_kernel<<<2, 256, 0, stream>>>(emb, emaM, ws);
    assign_kernel<<<NPTS/128, 256, 0, stream>>>(enc, emb, out, ws);   // 1024 blocks
    scatter_kernel<<<256, 1024, 0, stream>>>(enc, emb, out, ws);
    finalize_kernel<<<(KCODES*DIM)/256, 256, 0, stream>>>(emam, emaM, out, ws);
}

// Round 15
// 231.619 us; speedup vs baseline: 1.4118x; 1.0288x over previous
//
#include <hip/hip_runtime.h>

#define KCODES 512
#define DIM 64
#define NB 32
#define NH 64
#define NW 64
#define NPTS (NB*NH*NW)     // 131072
#define HW (NH*NW)          // 4096

// ---- output layout (floats) ----
#define O_OUT  0
#define O_LOSS 8388608
#define O_IDX  8388609
#define O_EMB  8519681
#define O_M    8552449
#define O_MM   8585217

// ---- workspace layout (floats) ----
#define W_DM   0                    // 32768
#define W_CNT  32768                // 512
#define W_LOSS 33280                // 1
#define W_SUMM 33281                // 1: sum of ema_M input
#define W_C    33282                // 512 codeword sq-norms
#define W_ZERO 33282                // memset extent (W_DM..W_SUMM)

#define XPAD 68
#define EPAD 68

// cnorm + side-effect: Sigma(ema_M) for the closed-form Ntot
__global__ void cnorm_kernel(const float* __restrict__ emb,
                             const float* __restrict__ emaM,
                             float* __restrict__ ws) {
    int k = blockIdx.x * blockDim.x + threadIdx.x;
    if (k >= KCODES) return;
    float s = 0.f;
    #pragma unroll
    for (int d = 0; d < DIM; ++d) { float v = emb[k*DIM + d]; s += v*v; }
    ws[W_C + k] = s;
    float m = emaM[k];
    #pragma unroll
    for (int off = 32; off >= 1; off >>= 1) m += __shfl_down(m, off, 64);
    if ((k & 63) == 0) atomicAdd(&ws[W_SUMM], m);
}

// r9/r14 proven assign. r15 change: thread-local scan uses STRICT < only --
// k is strictly increasing within a thread's scan, so the (s==best && k<bidx)
// tie-break could never fire; deleting it removes ~2 VALU ops per scan step
// (bit-identical outputs). Cross-lane reduce keeps the tie-break.
__global__ __launch_bounds__(256, 2) void assign_kernel(
    const float* __restrict__ enc, const float* __restrict__ emb,
    float* __restrict__ out, float* __restrict__ ws)
{
    __shared__ float XL[128*XPAD];   // [point][d]
    __shared__ float EL[128*EPAD];   // [cw][d]
    __shared__ float cnT[128];
    __shared__ int   bestI[128];

    const int t  = threadIdx.x;
    const int tx = t & 15;
    const int ty = t >> 4;
    const int wv = t >> 6, w = t & 63;
    const int R0 = blockIdx.x * 2;

    #pragma unroll
    for (int r2 = 0; r2 < 2; ++r2) {
        int R = R0 + r2, b = R >> 6, h = R & 63;
        const float* base = enc + (size_t)b*64*HW + (size_t)h*64 + w;
        int p = r2*64 + w;
        #pragma unroll
        for (int it = 0; it < 4; ++it) {
            int d0 = (it*4 + wv)*4;
            float4 v = make_float4(base[(size_t)(d0+0)*HW], base[(size_t)(d0+1)*HW],
                                   base[(size_t)(d0+2)*HW], base[(size_t)(d0+3)*HW]);
            *(float4*)(&XL[p*XPAD + d0]) = v;
        }
    }

    float best[8]; int bidx[8];
    #pragma unroll
    for (int i = 0; i < 8; ++i) { best[i] = 3.402823466e38f; bidx[i] = 0; }

    for (int tile = 0; tile < 4; ++tile) {
        __syncthreads();             // prior tile's EL reads done
        const float* esrc = emb + (size_t)tile*128*64;
        #pragma unroll
        for (int it = 0; it < 8; ++it) {
            int idx = t + it*256;
            *(float4*)(&EL[(idx >> 4)*EPAD + (idx & 15)*4]) =
                *(const float4*)(esrc + (idx >> 4)*64 + (idx & 15)*4);
        }
        if (t < 128) cnT[t] = ws[W_C + tile*128 + t];
        __syncthreads();

        float acc[8][8];
        #pragma unroll
        for (int i = 0; i < 8; ++i)
            #pragma unroll
            for (int j = 0; j < 8; ++j) acc[i][j] = 0.f;

        for (int c = 0; c < 16; ++c) {
            float4 xf[8], ef[8];
            #pragma unroll
            for (int i = 0; i < 8; ++i) {    // 4-address broadcast reads
                int p = 2*ty + (i&1) + 32*(i>>1);
                xf[i] = *(const float4*)(&XL[p*XPAD + c*4]);
            }
            #pragma unroll
            for (int j = 0; j < 8; ++j) {    // 2-way on bank quads = free
                int r = tx + 16*j;
                ef[j] = *(const float4*)(&EL[r*EPAD + c*4]);
            }
            #pragma unroll
            for (int i = 0; i < 8; ++i)
                #pragma unroll
                for (int j = 0; j < 8; ++j) {
                    acc[i][j] = fmaf(xf[i].x, ef[j].x, acc[i][j]);
                    acc[i][j] = fmaf(xf[i].y, ef[j].y, acc[i][j]);
                    acc[i][j] = fmaf(xf[i].z, ef[j].z, acc[i][j]);
                    acc[i][j] = fmaf(xf[i].w, ef[j].w, acc[i][j]);
                }
        }

        #pragma unroll
        for (int j = 0; j < 8; ++j) {
            int k = tile*128 + tx + 16*j;
            float cn = cnT[tx + 16*j];
            #pragma unroll
            for (int i = 0; i < 8; ++i) {
                float s = cn - 2.f*acc[i][j];
                if (s < best[i]) { best[i] = s; bidx[i] = k; }  // k strictly
            }                                                   // increasing
        }
    }

    // cross-lane argmin over the 16 tx-lanes sharing each point
    #pragma unroll
    for (int i = 0; i < 8; ++i) {
        float b = best[i]; int kx = bidx[i];
        #pragma unroll
        for (int off = 1; off < 16; off <<= 1) {
            float ob = __shfl_xor(b, off, 64);
            int   ok = __shfl_xor(kx, off, 64);
            if (ob < b || (ob == b && ok < kx)) { b = ob; kx = ok; }
        }
        if (tx == 0) bestI[2*ty + (i&1) + 32*(i>>1)] = kx;
    }
    __syncthreads();
    if (t < 128) out[O_IDX + (size_t)R0*64 + t] = (float)bestI[t];
}

// scatter v3: r14's role-split 16-wave kernel + per-wave dim ROTATION so the
// 8 accumulate-waves hit hot codewords at different (kb,d) at any instant
// (LDS same-address RMW serialization decorrelated). Rotation is a bijection
// over d per wave -> every (point,dim) still visited exactly once.
__global__ __launch_bounds__(1024, 1) void scatter_kernel(
    const float* __restrict__ enc, const float* __restrict__ emb,
    float* __restrict__ out, float* __restrict__ ws)
{
    __shared__ float dmL[KCODES][DIM+1];
    __shared__ float cntL[KCODES];
    __shared__ float redL[16];

    const int t  = threadIdx.x;
    const int w  = t & 63;
    const int wv = t >> 6;           // 0..15
    const int rw = wv & 7;           // row slot
    const int role = wv >> 3;        // 0: accumulate, 1: gather/store/loss
    const int pg = w >> 4, dl = w & 15;
    const int drot = (wv & 7) * 8;   // per-wave dim rotation

    float* dmf = &dmL[0][0];
    for (int i = t; i < KCODES*(DIM+1); i += 1024) dmf[i] = 0.f;
    if (t < KCODES) cntL[t] = 0.f;
    __syncthreads();

    const int R = blockIdx.x * 8 + rw;
    const int b = R >> 6, h = R & 63;
    const float* base  = enc + (size_t)b*(64*HW) + (size_t)h*64;
    float*       obase = out + O_OUT + (size_t)b*(64*HW) + (size_t)h*64;

    const int bidx = (int)out[O_IDX + (size_t)R*64 + w];
    float lsum = 0.f;

    if (role == 0) {
        atomicAdd(&cntL[bidx], 1.0f);
        #pragma unroll
        for (int c = 0; c < 4; ++c) {
            #pragma unroll
            for (int jj = 0; jj < 16; ++jj) {
                int p  = jj*4 + pg;
                int kb = __shfl(bidx, p, 64);
                int d  = (c*16 + dl + drot) & 63;
                atomicAdd(&dmL[kb][d], base[(size_t)d*HW + p]);
            }
        }
    } else {
        #pragma unroll
        for (int c = 0; c < 4; ++c) {
            #pragma unroll
            for (int jj = 0; jj < 16; ++jj) {
                int p  = jj*4 + pg;
                int kb = __shfl(bidx, p, 64);
                int d  = (c*16 + dl + drot) & 63;
                float xv = base[(size_t)d*HW + p];
                float q  = emb[kb*64 + d];
                obase[(size_t)d*HW + p] = q;
                float df = q - xv;
                lsum = fmaf(df, df, lsum);
            }
        }
    }

    #pragma unroll
    for (int off = 32; off >= 1; off >>= 1) lsum += __shfl_down(lsum, off, 64);
    if (w == 0) redL[wv] = lsum;
    __syncthreads();
    if (t == 0) {
        float s = 0.f;
        #pragma unroll
        for (int v = 8; v < 16; ++v) s += redL[v];
        atomicAdd(&ws[W_LOSS], s);
    }

    // flush: wave wv owns 32 rows; lane = dim (coalesced 256B atomic runs)
    for (int k = wv*32; k < wv*32 + 32; ++k) {
        float c = cntL[k];
        if (c == 0.f) continue;
        atomicAdd(&ws[W_DM + k*64 + w], dmL[k][w]);
        if (w == 0) atomicAdd(&ws[W_CNT + k], c);
    }
}

// Single fully-parallel finalize: Ntot closed form (0.99*SumEmaM + 0.01*NPTS)
__global__ void finalize_kernel(const float* __restrict__ emam,
                                const float* __restrict__ emaM,
                                float* __restrict__ out,
                                const float* __restrict__ ws)
{
    int i = blockIdx.x * blockDim.x + threadIdx.x;  // 0..32767
    int k = i >> 6;
    float Ntot = 0.99f * ws[W_SUMM] + 0.01f * (float)NPTS;
    float nM = 0.99f * emaM[k] + 0.01f * ws[W_CNT + k];
    float sm = (nM + 1e-5f) / (Ntot + 1e-5f * (float)KCODES) * Ntot;
    float nm = 0.99f * emam[i] + 0.01f * ws[W_DM + i];
    out[O_M + i] = nm;
    out[O_EMB + i] = nm / sm;
    if ((i & 63) == 0) out[O_MM + k] = sm;
    if (i == 0) out[O_LOSS] = 0.25f * ws[W_LOSS] / (float)((size_t)NPTS * DIM);
}

extern "C" void kernel_launch(void* const* d_in, const int* in_sizes, int n_in,
                              void* d_out, int out_size, void* d_ws, size_t ws_size,
                              hipStream_t stream)
{
    const float* enc  = (const float*)d_in[0];
    const float* emb  = (const float*)d_in[1];
    const float* emam = (const float*)d_in[2];
    const float* emaM = (const float*)d_in[3];
    float* out = (float*)d_out;
    float* ws  = (float*)d_ws;

    hipMemsetAsync(ws, 0, (size_t)W_ZERO * sizeof(float), stream);
    cnorm_kernel<<<2, 256, 0, stream>>>(emb, emaM, ws);
    assign_kernel<<<NPTS/128, 256, 0, stream>>>(enc, emb, out, ws);   // 1024 blocks
    scatter_kernel<<<256, 1024, 0, stream>>>(enc, emb, out, ws);
    finalize_kernel<<<(KCODES*DIM)/256, 256, 0, stream>>>(emam, emaM, out, ws);
}